// Round 11
// baseline (54.362 us; speedup 1.0000x reference)
//
#include <hip/hip_runtime.h>
#include <hip/hip_bf16.h>

// SimCLR loss, MI355X. N=8192 rows, D=128, T=0.5.
// R11 = DECOMPOSITION EXPERIMENT: identical to R10 except k_main is launched
// TWICE (idempotent pure-assignment writes -> same output, deterministic).
// T11 - T10 = true k_main duration in timing mode, resolving the 4-5x
// model-vs-measurement discrepancy (hw-floor math says ~5-7us; totals imply
// ~28us; k_main hasn't appeared in any profile since R4 due to fill crowding).

#define BATCH 4096
#define N_TOT 8192
#define DIM 128
#define GRP 128
#define NGRP 64
#define TILE_C 64                         // cols per LDS B-tile (16 KB)
#define NTASK 2080                        // 64*65/2

// exp(2d) == exp2(d * 2/ln2)
#define C_LOG2E2 2.8853900817779268f

using bf16x8 = __attribute__((ext_vector_type(8))) __bf16;
using f32x4  = __attribute__((ext_vector_type(4))) float;

typedef __attribute__((address_space(1))) const void cg_void;
typedef __attribute__((address_space(3))) void lds_void;
__device__ __forceinline__ void gll16(const void* g, void* l) {
    __builtin_amdgcn_global_load_lds((cg_void*)g, (lds_void*)l, 16, 0, 0);
}

// ---------------- kernel 1: normalize rows, write bf16 ----------------
__global__ __launch_bounds__(256) void k_normalize(const float* __restrict__ zi,
                                                   const float* __restrict__ zj,
                                                   __hip_bfloat16* __restrict__ zn) {
    int row  = blockIdx.x * 4 + (threadIdx.x >> 6);
    int lane = threadIdx.x & 63;
    const float* src = (row < BATCH) ? (zi + (size_t)row * DIM)
                                     : (zj + (size_t)(row - BATCH) * DIM);
    float2 v = ((const float2*)src)[lane];
    float ss = v.x * v.x + v.y * v.y;
    #pragma unroll
    for (int m = 1; m < 64; m <<= 1) ss += __shfl_xor(ss, m);
    float inv = 1.0f / fmaxf(sqrtf(ss), 1e-8f);
    __hip_bfloat162 o;
    o.x = __float2bfloat16(v.x * inv);
    o.y = __float2bfloat16(v.y * inv);
    ((__hip_bfloat162*)(zn + (size_t)row * DIM))[lane] = o;
}

// ---------------- kernel 2: one 128x128 triangle task per block ----------------
__global__ __launch_bounds__(256, 3) void k_main(const __hip_bfloat16* __restrict__ zn_,
                                                 float* __restrict__ S_contrib) {
    __shared__ __align__(16) char Bs[2][TILE_C * 256];       // 32 KB
    __shared__ float colred[4][GRP];                         // 2 KB

    const int tid  = threadIdx.x;
    const int lane = tid & 63;
    const int wv   = tid >> 6;                        // 0..3
    const int l15  = lane & 15;
    const int lb   = lane >> 4;                       // 0..3

    // O(1) triangle decode: base(I) = 64*I - I*(I-1)/2, row length 64-I
    const int idx = blockIdx.x;
    int I = (int)(64.5f - sqrtf(64.5f * 64.5f - 2.0f * (float)idx));
    int base = 64 * I - ((I * (I - 1)) >> 1);
    if (idx < base)                 { --I; base = 64 * I - ((I * (I - 1)) >> 1); }
    else if (idx >= base + 64 - I)  { ++I; base = 64 * I - ((I * (I - 1)) >> 1); }
    const int J = I + (idx - base);
    const bool isdiag = (I == J);

    const int wr0 = I * GRP + wv * 32;

    const __bf16* zn = (const __bf16*)zn_;

    // A fragments: rows wr0 + g*16 + l15 (g=0,1), k-slice s: k = s*32 + lb*8..+7
    bf16x8 a_[2][4];
    #pragma unroll
    for (int g = 0; g < 2; ++g) {
        const __bf16* p = zn + (size_t)(wr0 + g * 16 + l15) * DIM + lb * 8;
        #pragma unroll
        for (int s = 0; s < 4; ++s)
            a_[g][s] = *(const bf16x8*)(p + s * 32);
    }

    // stage BOTH 64-col tiles up front (8 gll16/thread). LDS granule
    // (col, slot) at col*256+slot*16 holds global k-chunk slot^(col&7)
    const char* gB = (const char*)(zn + (size_t)J * GRP * DIM);
    {
        int srcoff[4];
        #pragma unroll
        for (int i = 0; i < 4; ++i) {
            int m2 = (wv * 4 + i) * 64 + lane;
            int col = m2 >> 4, slot = m2 & 15;
            srcoff[i] = col * 256 + (slot ^ (col & 7)) * 16;
        }
        #pragma unroll
        for (int t = 0; t < 2; ++t) {
            const char* src = gB + (size_t)t * (TILE_C * 256);
            #pragma unroll
            for (int i = 0; i < 4; ++i)               // dest: uniform + lane*16
                gll16(src + srcoff[i], Bs[t] + (wv * 4 + i) * 1024);
        }
    }

    f32x4 sumexp[2] = {};                             // row-direction sums

    __syncthreads();                                  // drains gll16 (vmcnt 0)

    auto CMP = [&](int t) {
        const char* buf = Bs[t];
        const int c0t = J * GRP + t * TILE_C;
        const bool diagtile = ((unsigned)(wr0 - c0t) < (unsigned)TILE_C); // wave-uniform
        float csr4[4];
        #pragma unroll
        for (int cb = 0; cb < 4; ++cb) {
            const int cc = cb * 16 + l15;             // local col in tile
            const char* pc = buf + cc * 256;
            bf16x8 b[4];
            #pragma unroll
            for (int s = 0; s < 4; ++s)
                b[s] = *(const bf16x8*)(pc + ((lb + s * 4) ^ (cc & 7)) * 16);
            f32x4 acc[2] = {};
            #pragma unroll
            for (int g = 0; g < 2; ++g)
                #pragma unroll
                for (int s = 0; s < 4; ++s)
                    acc[g] = __builtin_amdgcn_mfma_f32_16x16x32_bf16(a_[g][s], b[s], acc[g], 0, 0, 0);
            // C layout: col = c0t+cc, row = wr0+g*16+lb*4+v
            const int mycol = c0t + cc;
            if (diagtile) {
                #pragma unroll
                for (int g = 0; g < 2; ++g)
                    #pragma unroll
                    for (int v = 0; v < 4; ++v) {
                        float e = __builtin_amdgcn_exp2f(acc[g][v] * C_LOG2E2);
                        int row = wr0 + g * 16 + lb * 4 + v;
                        sumexp[g][v] += (mycol == row) ? 0.0f : e;   // exclude self
                    }
                csr4[cb] = 0.0f;
            } else {
                float cs = 0.0f;
                #pragma unroll
                for (int g = 0; g < 2; ++g)
                    #pragma unroll
                    for (int v = 0; v < 4; ++v) {
                        float e = __builtin_amdgcn_exp2f(acc[g][v] * C_LOG2E2);
                        sumexp[g][v] += e;
                        cs += e;
                    }
                csr4[cb] = cs;
            }
        }
        if (!isdiag) {                                // flush tile's colsums
            #pragma unroll
            for (int cb = 0; cb < 4; ++cb) {
                float v = csr4[cb];
                v += __shfl_xor(v, 16);
                v += __shfl_xor(v, 32);
                if (lb == 0) colred[wv][t * TILE_C + cb * 16 + l15] = v;
            }
        }
    };

    CMP(0);
    CMP(1);

    // row-direction: reduce across the 16 lanes (cols) sharing each row,
    // write slot J for rows of group I
    #pragma unroll
    for (int m = 1; m <= 8; m <<= 1)
        #pragma unroll
        for (int g = 0; g < 2; ++g)
            #pragma unroll
            for (int v = 0; v < 4; ++v)
                sumexp[g][v] += __shfl_xor(sumexp[g][v], m);

    if (l15 == 0) {
        #pragma unroll
        for (int g = 0; g < 2; ++g) {
            int row = wr0 + g * 16 + lb * 4;
            *(f32x4*)&S_contrib[(size_t)J * N_TOT + row] = sumexp[g];
        }
    }

    // col-direction: combine 4 waves, write slot I for rows of group J
    if (!isdiag) {
        __syncthreads();
        if (tid < GRP) {
            float s = colred[0][tid] + colred[1][tid] + colred[2][tid] + colred[3][tid];
            S_contrib[(size_t)I * N_TOT + J * GRP + tid] = s;
        }
    }
}

// bf16-pair dot helper (uint = 2 packed bf16)
__device__ inline float bdot(unsigned a, unsigned b) {
    float alo = __uint_as_float(a << 16), ahi = __uint_as_float(a & 0xffff0000u);
    float blo = __uint_as_float(b << 16), bhi = __uint_as_float(b & 0xffff0000u);
    return fmaf(alo, blo, ahi * bhi);
}

// ---------------- kernel 3: per-row loss (all 64 slots valid) ----------------
__global__ __launch_bounds__(256) void k_rowsum(const float* __restrict__ S_contrib,
                                                const __hip_bfloat16* __restrict__ zn_,
                                                float* __restrict__ blk_out) {
    const int r = blockIdx.x * 256 + threadIdx.x;
    float S = 0.0f;
    #pragma unroll
    for (int s = 0; s < NGRP; ++s) S += S_contrib[(size_t)s * N_TOT + r];

    const uint4* pa = (const uint4*)((const __bf16*)zn_ + (size_t)r * DIM);
    const uint4* pb = (const uint4*)((const __bf16*)zn_ + (size_t)(r ^ BATCH) * DIM);
    float dot = 0.0f;
    #pragma unroll
    for (int cc = 0; cc < DIM / 8; ++cc) {
        uint4 ua = pa[cc], ub = pb[cc];
        dot += bdot(ua.x, ub.x) + bdot(ua.y, ub.y) + bdot(ua.z, ub.z) + bdot(ua.w, ub.w);
    }

    float contrib = __logf(S) - 2.0f * dot;

    #pragma unroll
    for (int m = 1; m < 64; m <<= 1) contrib += __shfl_xor(contrib, m);
    __shared__ float sm[4];
    if ((threadIdx.x & 63) == 0) sm[threadIdx.x >> 6] = contrib;
    __syncthreads();
    if (threadIdx.x == 0) blk_out[blockIdx.x] = sm[0] + sm[1] + sm[2] + sm[3];
}

// ---------------- kernel 4: final scalar ----------------
__global__ void k_final(const float* __restrict__ blk_out, float* __restrict__ out) {
    float v = (threadIdx.x < 32) ? blk_out[threadIdx.x] : 0.0f;
    #pragma unroll
    for (int m = 1; m < 64; m <<= 1) v += __shfl_xor(v, m);
    if (threadIdx.x == 0) out[0] = v / (float)N_TOT;
}

extern "C" void kernel_launch(void* const* d_in, const int* in_sizes, int n_in,
                              void* d_out, int out_size, void* d_ws, size_t ws_size,
                              hipStream_t stream) {
    const float* zi = (const float*)d_in[0];
    const float* zj = (const float*)d_in[1];
    char* ws = (char*)d_ws;
    __hip_bfloat16* zn = (__hip_bfloat16*)ws;                        // 2 MB
    float* S_contrib = (float*)(ws + (size_t)2 * 1024 * 1024);       // 2 MB (64 slots)
    float* blk       = (float*)(ws + (size_t)4 * 1024 * 1024);       // 128 B
    float* out       = (float*)d_out;

    k_normalize<<<N_TOT / 4, 256, 0, stream>>>(zi, zj, zn);
    // ABLATION: k_main twice. Idempotent (pure assignments of identical
    // values) -> output unchanged; T11 - T10 = one k_main duration.
    k_main<<<NTASK, 256, 0, stream>>>(zn, S_contrib);
    k_main<<<NTASK, 256, 0, stream>>>(zn, S_contrib);
    k_rowsum<<<N_TOT / 256, 256, 0, stream>>>(S_contrib, zn, blk);
    k_final<<<1, 64, 0, stream>>>(blk, out);
}

// Round 12
// 49.695 us; speedup vs baseline: 1.0939x; 1.0939x over previous
//
#include <hip/hip_runtime.h>
#include <hip/hip_bf16.h>

// SimCLR loss, MI355X. N=8192 rows, D=128, T=0.5.
// R12: (1) k_main LDS = exactly 32KB (colred aliases Bs[0], flushed after a
// post-compute barrier; colsum partials carried in 8 regs) -> 5 blocks/CU,
// + s_setprio around MFMA clusters. (2) k_final fused into k_rowsum via
// device-scope ticket (fixed-order final sum -> deterministic). (3) pos-dot
// extracted in k_main's (I,I+32) tasks -> k_rowsum drops all zn reads.
// R11 decomposition: k_main 17.2us, others ~20us (mostly launch overhead).

#define BATCH 4096
#define N_TOT 8192
#define DIM 128
#define GRP 128
#define NGRP 64
#define TILE_C 64                         // cols per LDS B-tile (16 KB)
#define NTASK 2080                        // 64*65/2

// exp(2d) == exp2(d * 2/ln2)
#define C_LOG2E2 2.8853900817779268f

using bf16x8 = __attribute__((ext_vector_type(8))) __bf16;
using f32x4  = __attribute__((ext_vector_type(4))) float;

typedef __attribute__((address_space(1))) const void cg_void;
typedef __attribute__((address_space(3))) void lds_void;
__device__ __forceinline__ void gll16(const void* g, void* l) {
    __builtin_amdgcn_global_load_lds((cg_void*)g, (lds_void*)l, 16, 0, 0);
}

// ---------------- kernel 1: normalize rows -> bf16; zero the ticket ----------------
__global__ __launch_bounds__(256) void k_normalize(const float* __restrict__ zi,
                                                   const float* __restrict__ zj,
                                                   __hip_bfloat16* __restrict__ zn,
                                                   int* __restrict__ ticket) {
    if (blockIdx.x == 0 && threadIdx.x == 0) *ticket = 0;   // reset for k_rowsum
    int lane = threadIdx.x & 63;
    int wv   = threadIdx.x >> 6;
    for (int row = blockIdx.x * 4 + wv; row < N_TOT; row += 512 * 4) {
        const float* src = (row < BATCH) ? (zi + (size_t)row * DIM)
                                         : (zj + (size_t)(row - BATCH) * DIM);
        float2 v = ((const float2*)src)[lane];
        float ss = v.x * v.x + v.y * v.y;
        #pragma unroll
        for (int m = 1; m < 64; m <<= 1) ss += __shfl_xor(ss, m);
        float inv = 1.0f / fmaxf(sqrtf(ss), 1e-8f);
        __hip_bfloat162 o;
        o.x = __float2bfloat16(v.x * inv);
        o.y = __float2bfloat16(v.y * inv);
        ((__hip_bfloat162*)(zn + (size_t)row * DIM))[lane] = o;
    }
}

// ---------------- kernel 2: one 128x128 triangle task per block ----------------
__global__ __launch_bounds__(256, 3) void k_main(const __hip_bfloat16* __restrict__ zn_,
                                                 float* __restrict__ S_contrib,
                                                 float* __restrict__ pos) {
    __shared__ __align__(16) char Bs[2][TILE_C * 256];       // 32 KB total (exact)
    float* colred = (float*)Bs;                              // aliases Bs[0]; used
                                                             // only after barrier
    const int tid  = threadIdx.x;
    const int lane = tid & 63;
    const int wv   = tid >> 6;                        // 0..3
    const int l15  = lane & 15;
    const int lb   = lane >> 4;                       // 0..3

    // O(1) triangle decode: base(I) = 64*I - I*(I-1)/2
    const int idx = blockIdx.x;
    int I = (int)(64.5f - sqrtf(64.5f * 64.5f - 2.0f * (float)idx));
    int base = 64 * I - ((I * (I - 1)) >> 1);
    if (idx < base)                 { --I; base = 64 * I - ((I * (I - 1)) >> 1); }
    else if (idx >= base + 64 - I)  { ++I; base = 64 * I - ((I * (I - 1)) >> 1); }
    const int J = I + (idx - base);
    const bool isdiag = (I == J);
    const bool haspos = (J == I + 32);                // tasks containing (r, r+4096)

    const int wr0 = I * GRP + wv * 32;

    const __bf16* zn = (const __bf16*)zn_;

    // A fragments: rows wr0 + g*16 + l15 (g=0,1), k-slice s: k = s*32 + lb*8..+7
    bf16x8 a_[2][4];
    #pragma unroll
    for (int g = 0; g < 2; ++g) {
        const __bf16* p = zn + (size_t)(wr0 + g * 16 + l15) * DIM + lb * 8;
        #pragma unroll
        for (int s = 0; s < 4; ++s)
            a_[g][s] = *(const bf16x8*)(p + s * 32);
    }

    // stage BOTH 64-col tiles up front. LDS granule (col, slot) at
    // col*256+slot*16 holds global k-chunk slot^(col&7) (rule #21).
    const char* gB = (const char*)(zn + (size_t)J * GRP * DIM);
    {
        int srcoff[4];
        #pragma unroll
        for (int i = 0; i < 4; ++i) {
            int m2 = (wv * 4 + i) * 64 + lane;
            int col = m2 >> 4, slot = m2 & 15;
            srcoff[i] = col * 256 + (slot ^ (col & 7)) * 16;
        }
        #pragma unroll
        for (int t = 0; t < 2; ++t) {
            const char* src = gB + (size_t)t * (TILE_C * 256);
            #pragma unroll
            for (int i = 0; i < 4; ++i)               // dest: uniform + lane*16
                gll16(src + srcoff[i], Bs[t] + (wv * 4 + i) * 1024);
        }
    }

    f32x4 sumexp[2] = {};                             // row-direction sums
    float csr[2][4];                                  // colsum partials (regs)

    __syncthreads();                                  // drains gll16 (vmcnt 0)

    auto CMP = [&](int t) {
        const char* buf = Bs[t];
        const int c0t = J * GRP + t * TILE_C;
        const bool diagtile = ((unsigned)(wr0 - c0t) < (unsigned)TILE_C); // wave-uniform
        #pragma unroll
        for (int cb = 0; cb < 4; ++cb) {
            const int cc = cb * 16 + l15;             // local col in tile
            const char* pc = buf + cc * 256;
            bf16x8 b[4];
            #pragma unroll
            for (int s = 0; s < 4; ++s)
                b[s] = *(const bf16x8*)(pc + ((lb + s * 4) ^ (cc & 7)) * 16);
            f32x4 acc[2] = {};
            __builtin_amdgcn_s_setprio(1);
            #pragma unroll
            for (int g = 0; g < 2; ++g)
                #pragma unroll
                for (int s = 0; s < 4; ++s)
                    acc[g] = __builtin_amdgcn_mfma_f32_16x16x32_bf16(a_[g][s], b[s], acc[g], 0, 0, 0);
            __builtin_amdgcn_s_setprio(0);
            // C layout: col = c0t+cc, row = wr0+g*16+lb*4+v
            const int mycol = c0t + cc;
            if (haspos) {                             // 32 of 2080 blocks
                #pragma unroll
                for (int g = 0; g < 2; ++g)
                    #pragma unroll
                    for (int v = 0; v < 4; ++v) {
                        int row = wr0 + g * 16 + lb * 4 + v;
                        if (mycol == row + BATCH) pos[row] = acc[g][v];
                    }
            }
            if (diagtile) {                           // only inside diag blocks
                #pragma unroll
                for (int g = 0; g < 2; ++g)
                    #pragma unroll
                    for (int v = 0; v < 4; ++v) {
                        float e = __builtin_amdgcn_exp2f(acc[g][v] * C_LOG2E2);
                        int row = wr0 + g * 16 + lb * 4 + v;
                        sumexp[g][v] += (mycol == row) ? 0.0f : e;   // exclude self
                    }
                csr[t][cb] = 0.0f;
            } else {
                float cs = 0.0f;
                #pragma unroll
                for (int g = 0; g < 2; ++g)
                    #pragma unroll
                    for (int v = 0; v < 4; ++v) {
                        float e = __builtin_amdgcn_exp2f(acc[g][v] * C_LOG2E2);
                        sumexp[g][v] += e;
                        cs += e;
                    }
                csr[t][cb] = cs;
            }
        }
    };

    CMP(0);
    CMP(1);

    // row-direction: reduce across the 16 lanes (cols) sharing each row,
    // write slot J for rows of group I
    #pragma unroll
    for (int m = 1; m <= 8; m <<= 1)
        #pragma unroll
        for (int g = 0; g < 2; ++g)
            #pragma unroll
            for (int v = 0; v < 4; ++v)
                sumexp[g][v] += __shfl_xor(sumexp[g][v], m);

    if (l15 == 0) {
        #pragma unroll
        for (int g = 0; g < 2; ++g) {
            int row = wr0 + g * 16 + lb * 4;
            *(f32x4*)&S_contrib[(size_t)J * N_TOT + row] = sumexp[g];
        }
    }

    // col-direction (off-diag only): all Bs reads are done -> safe to alias.
    if (!isdiag) {
        __syncthreads();                              // Bs dead; colred alive
        #pragma unroll
        for (int t = 0; t < 2; ++t)
            #pragma unroll
            for (int cb = 0; cb < 4; ++cb) {
                float v = csr[t][cb];
                v += __shfl_xor(v, 16);
                v += __shfl_xor(v, 32);
                if (lb == 0) colred[wv * GRP + t * TILE_C + cb * 16 + l15] = v;
            }
        __syncthreads();
        if (tid < GRP) {
            float s = colred[0 * GRP + tid] + colred[1 * GRP + tid]
                    + colred[2 * GRP + tid] + colred[3 * GRP + tid];
            S_contrib[(size_t)I * N_TOT + J * GRP + tid] = s;
        }
    }
}

// ---------------- kernel 3: per-row loss + fused final reduce ----------------
// contrib_r = log(S_r) - 2*pos_dot_r. Last block (device-scope ticket) sums
// blk[0..31] in fixed index order -> bitwise deterministic.
__global__ __launch_bounds__(256) void k_rowsum(const float* __restrict__ S_contrib,
                                                const float* __restrict__ pos,
                                                float* __restrict__ blk,
                                                int* __restrict__ ticket,
                                                float* __restrict__ out) {
    const int r = blockIdx.x * 256 + threadIdx.x;
    float S = 0.0f;
    #pragma unroll
    for (int s = 0; s < NGRP; ++s) S += S_contrib[(size_t)s * N_TOT + r];

    float contrib = __logf(S) - 2.0f * pos[r & (BATCH - 1)];

    #pragma unroll
    for (int m = 1; m < 64; m <<= 1) contrib += __shfl_xor(contrib, m);
    __shared__ float sm[4];
    __shared__ int winner;
    if ((threadIdx.x & 63) == 0) sm[threadIdx.x >> 6] = contrib;
    __syncthreads();
    if (threadIdx.x == 0) {
        blk[blockIdx.x] = sm[0] + sm[1] + sm[2] + sm[3];
        __threadfence();                              // release blk store
        winner = (atomicAdd(ticket, 1) == 31);        // device-scope
    }
    __syncthreads();
    if (winner) {
        __threadfence();                              // acquire all blk stores
        if (threadIdx.x < 32) {
            float v = blk[threadIdx.x];
            #pragma unroll
            for (int m = 1; m < 32; m <<= 1) v += __shfl_xor(v, m);
            if (threadIdx.x == 0) out[0] = v / (float)N_TOT;
        }
    }
}

extern "C" void kernel_launch(void* const* d_in, const int* in_sizes, int n_in,
                              void* d_out, int out_size, void* d_ws, size_t ws_size,
                              hipStream_t stream) {
    const float* zi = (const float*)d_in[0];
    const float* zj = (const float*)d_in[1];
    char* ws = (char*)d_ws;
    __hip_bfloat16* zn = (__hip_bfloat16*)ws;                        // 2 MB
    float* S_contrib = (float*)(ws + (size_t)2 * 1024 * 1024);       // 2 MB (64 slots)
    float* blk       = (float*)(ws + (size_t)4 * 1024 * 1024);       // 128 B
    int*   ticket    = (int*)  (ws + (size_t)4 * 1024 * 1024 + 128);
    float* pos       = (float*)(ws + (size_t)4 * 1024 * 1024 + 256); // 16 KB
    float* out       = (float*)d_out;

    k_normalize<<<512, 256, 0, stream>>>(zi, zj, zn, ticket);
    k_main<<<NTASK, 256, 0, stream>>>(zn, S_contrib, pos);
    k_rowsum<<<N_TOT / 256, 256, 0, stream>>>(S_contrib, pos, blk, ticket, out);
}